// Round 1
// baseline (4437.010 us; speedup 1.0000x reference)
//
#include <hip/hip_runtime.h>

#define N_ROWS 65536
#define K_CODES 8192
#define DIM 256

// d_out layout (floats): [quantized_st 65536*256][loss 1][indices 65536]
#define LOSS_OFF (N_ROWS * DIM)
#define IDX_OFF (LOSS_OFF + 1)

// d_ws layout (floats)
#define WS_LOSS 0
#define WS_ZNORM 64
#define WS_WNORM (WS_ZNORM + N_ROWS)

// Opaque fp32 multiply: guarantees a separately-rounded product (numpy computes
// the z*z temp array, THEN pairwise-sums it; hipcc's default -ffp-contract=fast
// would otherwise fuse mul+add into fma and change the rounding).
__device__ __forceinline__ float mul_rn_nofma(float a, float b) {
  float r;
  asm("v_mul_f32 %0, %1, %2" : "=v"(r) : "v"(a), "v"(b));
  return r;
}

// numpy fp32 pairwise sum of squares over 256 contiguous floats.
// numpy pairwise_sum(n=256): split into two 128-blocks; each block uses 8
// stride-8 accumulators r[j] (init a[j], then r[j]+=a[i+j]) combined as
// ((r0+r1)+(r2+r3))+((r4+r5)+(r6+r7)); halves added together.
__device__ float row_sumsq_np(const float* __restrict__ p) {
  float blk[2];
#pragma unroll
  for (int b = 0; b < 2; ++b) {
    const float* q = p + b * 128;
    float r[8];
#pragma unroll
    for (int j = 0; j < 8; ++j) r[j] = mul_rn_nofma(q[j], q[j]);
    for (int i = 8; i < 128; i += 8) {
#pragma unroll
      for (int j = 0; j < 8; ++j) r[j] = r[j] + mul_rn_nofma(q[i + j], q[i + j]);
    }
    blk[b] = ((r[0] + r[1]) + (r[2] + r[3])) + ((r[4] + r[5]) + (r[6] + r[7]));
  }
  return blk[0] + blk[1];
}

__global__ void norms_kernel(const float* __restrict__ z, const float* __restrict__ W,
                             float* __restrict__ ws) {
  const int t = blockIdx.x * blockDim.x + threadIdx.x;
  if (t == 0) ws[WS_LOSS] = 0.0f;  // runs before gather_loss_kernel's atomics (stream order)
  if (t < N_ROWS) {
    ws[WS_ZNORM + t] = row_sumsq_np(z + (size_t)t * DIM);
  } else if (t < N_ROWS + K_CODES) {
    const int k = t - N_ROWS;
    ws[WS_WNORM + k] = row_sumsq_np(W + (size_t)k * DIM);
  }
}

// 64 z-rows x 128 codewords per block; 256 threads as 16(ty: 4 rows) x 16(tx: 8 cols).
// acc chain per (row,col) is a single sequential fmaf over d=0..255 ascending,
// matching BLAS sgemm's per-element k-order FMA accumulation.
__global__ __launch_bounds__(256, 2) void gemm_argmin_kernel(
    const float* __restrict__ z, const float* __restrict__ W,
    const float* __restrict__ ws, float* __restrict__ out) {
  __shared__ float zsT[DIM][64];   // [d][row]  64 KB, persistent
  __shared__ float wsT[32][128];   // [dd][col] 16 KB, per d-chunk

  const int tid = threadIdx.x;
  const int tx = tid & 15;
  const int ty = tid >> 4;
  const int rowBase = blockIdx.x * 64;

  // Stage z tile transposed (once). Each wave loads one full row (64 float4, 1 KB).
#pragma unroll
  for (int i = 0; i < 16; ++i) {
    const int id = i * 256 + tid;  // float4 id 0..4095
    const int r = id >> 6;         // row 0..63
    const int c4 = id & 63;        // float4 col 0..63
    const float4 v = *(const float4*)(z + (size_t)(rowBase + r) * DIM + c4 * 4);
    zsT[c4 * 4 + 0][r] = v.x;
    zsT[c4 * 4 + 1][r] = v.y;
    zsT[c4 * 4 + 2][r] = v.z;
    zsT[c4 * 4 + 3][r] = v.w;
  }

  float znr[4];
#pragma unroll
  for (int r = 0; r < 4; ++r) znr[r] = ws[WS_ZNORM + rowBase + ty * 4 + r];

  float bestD[4];
  int bestI[4];
#pragma unroll
  for (int r = 0; r < 4; ++r) { bestD[r] = 3.0e38f; bestI[r] = 0; }

  for (int kt = 0; kt < K_CODES / 128; ++kt) {
    float acc[4][8];
#pragma unroll
    for (int r = 0; r < 4; ++r)
#pragma unroll
      for (int c = 0; c < 8; ++c) acc[r][c] = 0.0f;

    for (int dc = 0; dc < DIM / 32; ++dc) {
      __syncthreads();  // protect wsT (and first-iter zsT) vs previous reads
      // Stage W chunk transposed: cols kt*128..+127, d = dc*32..+31
#pragma unroll
      for (int i = 0; i < 4; ++i) {
        const int id = i * 256 + tid;  // float4 id 0..1023
        const int r = id >> 3;         // col 0..127
        const int c4 = id & 7;         // d-float4 0..7
        const float4 v =
            *(const float4*)(W + (size_t)(kt * 128 + r) * DIM + dc * 32 + c4 * 4);
        wsT[c4 * 4 + 0][r] = v.x;
        wsT[c4 * 4 + 1][r] = v.y;
        wsT[c4 * 4 + 2][r] = v.z;
        wsT[c4 * 4 + 3][r] = v.w;
      }
      __syncthreads();
#pragma unroll
      for (int dd = 0; dd < 32; ++dd) {
        const int d = dc * 32 + dd;
        const float4 za = *(const float4*)&zsT[d][ty * 4];
        const float4 wb0 = *(const float4*)&wsT[dd][tx * 8];
        const float4 wb1 = *(const float4*)&wsT[dd][tx * 8 + 4];
        const float zav[4] = {za.x, za.y, za.z, za.w};
        const float wbv[8] = {wb0.x, wb0.y, wb0.z, wb0.w, wb1.x, wb1.y, wb1.z, wb1.w};
#pragma unroll
        for (int r = 0; r < 4; ++r)
#pragma unroll
          for (int c = 0; c < 8; ++c) acc[r][c] = fmaf(zav[r], wbv[c], acc[r][c]);
      }
    }

    // Epilogue: dist = fl(fl(znorm+wnorm) - fl(2*acc)); strict < + ascending col
    // order keeps the first-occurrence (lowest index) semantics of np.argmin.
#pragma unroll
    for (int c = 0; c < 8; ++c) {
      const int col = kt * 128 + tx * 8 + c;
      const float wn = ws[WS_WNORM + col];
#pragma unroll
      for (int r = 0; r < 4; ++r) {
        const float t = znr[r] + wn;
        const float dist = t - 2.0f * acc[r][c];  // 2*acc exact; fma-contraction bit-identical
        if (dist < bestD[r]) { bestD[r] = dist; bestI[r] = col; }
      }
    }
  }

  // Butterfly reduce across the 16 tx lanes; ties -> lower index.
#pragma unroll
  for (int m = 1; m < 16; m <<= 1) {
#pragma unroll
    for (int r = 0; r < 4; ++r) {
      const float od = __shfl_xor(bestD[r], m, 64);
      const int oi = __shfl_xor(bestI[r], m, 64);
      if (od < bestD[r] || (od == bestD[r] && oi < bestI[r])) {
        bestD[r] = od;
        bestI[r] = oi;
      }
    }
  }
  if (tx == 0) {
#pragma unroll
    for (int r = 0; r < 4; ++r)
      out[IDX_OFF + rowBase + ty * 4 + r] = (float)bestI[r];
  }
}

// 64 rows per block: gather W[idx], write quantized_st = z + (q - z) (replicating
// the reference's rounding), accumulate sum (q-z)^2, one atomicAdd per block.
__global__ void gather_loss_kernel(const float* __restrict__ z, const float* __restrict__ W,
                                   float* __restrict__ out, float* __restrict__ ws) {
  const int tid = threadIdx.x;
  const int rowBase = blockIdx.x * 64;
  float lsum = 0.0f;
  for (int p = 0; p < 16; ++p) {
    const int row = rowBase + p * 4 + (tid >> 6);
    const int c4 = tid & 63;
    const int idx = (int)out[IDX_OFF + row];  // exact: idx <= 8191
    const float4 zv = *(const float4*)(z + (size_t)row * DIM + c4 * 4);
    const float4 qv = *(const float4*)(W + (size_t)idx * DIM + c4 * 4);
    float4 t, o;
    t.x = qv.x - zv.x; t.y = qv.y - zv.y; t.z = qv.z - zv.z; t.w = qv.w - zv.w;
    o.x = zv.x + t.x;  o.y = zv.y + t.y;  o.z = zv.z + t.z;  o.w = zv.w + t.w;
    *(float4*)(out + (size_t)row * DIM + c4 * 4) = o;
    lsum += t.x * t.x + t.y * t.y + t.z * t.z + t.w * t.w;
  }
#pragma unroll
  for (int m = 1; m < 64; m <<= 1) lsum += __shfl_xor(lsum, m, 64);
  __shared__ float part[4];
  if ((tid & 63) == 0) part[tid >> 6] = lsum;
  __syncthreads();
  if (tid == 0) atomicAdd(&ws[WS_LOSS], (part[0] + part[1]) + (part[2] + part[3]));
}

__global__ void finalize_kernel(const float* __restrict__ ws, float* __restrict__ out) {
  if (threadIdx.x == 0 && blockIdx.x == 0) {
    const float mean = ws[WS_LOSS] / (float)(N_ROWS * DIM);  // /2^24 exact scale
    out[LOSS_OFF] = mean + 0.25f * mean;  // q_latent + COMMITMENT_COST * e_latent
  }
}

extern "C" void kernel_launch(void* const* d_in, const int* in_sizes, int n_in,
                              void* d_out, int out_size, void* d_ws, size_t ws_size,
                              hipStream_t stream) {
  (void)in_sizes; (void)n_in; (void)out_size; (void)ws_size;
  const float* z = (const float*)d_in[0];
  const float* W = (const float*)d_in[1];
  float* out = (float*)d_out;
  float* ws = (float*)d_ws;

  hipLaunchKernelGGL(norms_kernel, dim3((N_ROWS + K_CODES) / 256), dim3(256), 0, stream,
                     z, W, ws);
  hipLaunchKernelGGL(gemm_argmin_kernel, dim3(N_ROWS / 64), dim3(256), 0, stream,
                     z, W, ws, out);
  hipLaunchKernelGGL(gather_loss_kernel, dim3(N_ROWS / 64), dim3(256), 0, stream,
                     z, W, out, ws);
  hipLaunchKernelGGL(finalize_kernel, dim3(1), dim3(64), 0, stream, ws, out);
}